// Round 4
// baseline (125.821 us; speedup 1.0000x reference)
//
#include <hip/hip_runtime.h>
#include <hip/hip_fp16.h>
#include <math.h>

#define BATCH 8
#define NSLOT 256
#define DDIM  256
#define HID   128
#define NREL  8

typedef _Float16 half8 __attribute__((ext_vector_type(8)));
typedef float float4v __attribute__((ext_vector_type(4)));

union U8 {
  uint32_t u[4];
  _Float16 f[8];
  half8 v;
  float4 f4;
};

union U4 {
  uint32_t u[2];
  _Float16 f[4];
  uint2 u2;
};

// ---------------------------------------------------------------------------
// R17: lean single kernel, c-strip streaming. R16 diagnosis: 42us exec from
// latency-bound structure (1 blk/CU, 2 waves/SIMD, 160 strided VMEM/thread).
// Fix: the HID contraction is separable (h[c]=relu(Pi[c]+Pj[c]); logits =
// sum_c h[c]W2[c,r]) -> stream c in 4 strips of 32 (one MFMA K each), with
// per-strip W staged [32c][256k] f16 in LDS via COALESCED float4 loads +
// register transpose. Grid 1024 x 256 (R14-pair shape: b x i0-of-8 x j64),
// 37.5KB LDS -> 4 blocks/CU, 4 waves/SIMD. acc[8] persists across strips.
//
// MFMA maps (HW-validated R5-R12 + R16):
//   A[m=lane&15][k=(lane>>4)*8+u], B[k=(lane>>4)*8+u][n=lane&15],
//   D[m=(lane>>4)*4+reg][n=lane&15].
// Pj^T trick (R16-validated): A=Wu-strip (m=c), B=slots^T (n=j) =>
//   D[m=c][n=j]; 4 D-regs = 4 consecutive c -> one b64 slab store.
// ---------------------------------------------------------------------------

// XOR swizzle bits 4..6 of within-row byte offset, keyed by row (R16-validated,
// bijective, applied identically on write and read).
__device__ __forceinline__ int swz(int row, int off) {
  return (off & ~0x70) | ((((off >> 4) ^ row) & 7) << 4);
}

__global__ __launch_bounds__(256, 4) void fused_kernel(
    const float* __restrict__ slots, const float* __restrict__ W1,
    const float* __restrict__ b1, const float* __restrict__ W2,
    const float* __restrict__ b2, float* __restrict__ out) {
  // LDS: W strips 2 x 16KB (swizzled [c_local 32][k 256] f16),
  //      PiS [8 i][32 c] f16 linear (reads are broadcast),
  //      Slab per-wave [16 j][40 f16] (pad 40: row stride 80B = 20 dwords,
  //      rows hit rotating bank groups -> ~2-way, free).
  __shared__ _Float16 WlS[32 * 256];
  __shared__ _Float16 WuS[32 * 256];
  __shared__ _Float16 PiS[8 * 32];
  __shared__ _Float16 SlabS[4][16][40];

  const int tid  = threadIdx.x;
  const int w    = tid >> 6;
  const int lane = tid & 63;
  const int lo16 = lane & 15;
  const int kg   = lane >> 4;

  const int bx  = blockIdx.x;
  const int b   = bx >> 7;
  const int i0  = ((bx >> 2) & 31) * 8;
  const int j0w = (bx & 3) * 64 + w * 16;  // wave's 16-j tile
  const float* sb = slots + (size_t)b * NSLOT * DDIM;

  // ---- Bs: slots^T B-frags for this wave's j-tile (held across strips) ----
  U8 Bs[8];
  {
    const float* srow = sb + (size_t)(j0w + lo16) * DDIM;
#pragma unroll
    for (int ks = 0; ks < 8; ++ks) {
      const float4 x0 = *(const float4*)(srow + ks * 32 + kg * 8);
      const float4 x1 = *(const float4*)(srow + ks * 32 + kg * 8 + 4);
      Bs[ks].f[0] = (_Float16)x0.x; Bs[ks].f[1] = (_Float16)x0.y;
      Bs[ks].f[2] = (_Float16)x0.z; Bs[ks].f[3] = (_Float16)x0.w;
      Bs[ks].f[4] = (_Float16)x1.x; Bs[ks].f[5] = (_Float16)x1.y;
      Bs[ks].f[6] = (_Float16)x1.z; Bs[ks].f[7] = (_Float16)x1.w;
    }
  }
  const float b2v = (lo16 < NREL) ? b2[lo16] : 0.0f;

  float4v acc[8];
#pragma unroll
  for (int i = 0; i < 8; ++i) acc[i] = (float4v){0.0f, 0.0f, 0.0f, 0.0f};

  for (int kq = 0; kq < 4; ++kq) {
    // ---- stage W strips: [c_local][k] f16, coalesced f4 + reg transpose ----
    {
      const int kg8 = tid >> 3;          // k-group 0..31 (8 k each)
      const int c4  = (tid & 7) * 4;     // c_local base 0..28
      const int cg  = kq * 32 + c4;      // global c
      float xr[32];
#pragma unroll
      for (int u = 0; u < 8; ++u)
        *(float4*)&xr[u * 4] = *(const float4*)(W1 + (size_t)(kg8 * 8 + u) * HID + cg);
#pragma unroll
      for (int j = 0; j < 4; ++j) {
        U8 p;
#pragma unroll
        for (int u = 0; u < 8; ++u) p.f[u] = (_Float16)xr[u * 4 + j];
        *(float4*)((char*)WlS + (c4 + j) * 512 + swz(c4 + j, kg8 * 16)) = p.f4;
      }
#pragma unroll
      for (int u = 0; u < 8; ++u)
        *(float4*)&xr[u * 4] =
            *(const float4*)(W1 + (size_t)(DDIM + kg8 * 8 + u) * HID + cg);
#pragma unroll
      for (int j = 0; j < 4; ++j) {
        U8 p;
#pragma unroll
        for (int u = 0; u < 8; ++u) p.f[u] = (_Float16)xr[u * 4 + j];
        *(float4*)((char*)WuS + (c4 + j) * 512 + swz(c4 + j, kg8 * 16)) = p.f4;
      }
    }

    // ---- W2 B-frag for this strip (L1-resident scalar loads) ----
    U8 w2s;
#pragma unroll
    for (int u = 0; u < 8; ++u) {
      const float v = W2[(kq * 32 + kg * 8 + u) * NREL + (lo16 & 7)];
      w2s.f[u] = (lo16 < NREL) ? (_Float16)v : (_Float16)0.0f;
    }

    __syncthreads();  // W strips visible

    // ---- Pj^T strip: 2 c-tiles x this wave's j-tile -> slab ----
#pragma unroll
    for (int ct = 0; ct < 2; ++ct) {
      const int row = ct * 16 + lo16;  // c_local as A-row m
      U8 af[8];
#pragma unroll
      for (int ks = 0; ks < 8; ++ks)
        af[ks].f4 = *(const float4*)((const char*)WuS + row * 512 +
                                     swz(row, ks * 64 + kg * 16));
      float4v d = {0.0f, 0.0f, 0.0f, 0.0f};
#pragma unroll
      for (int ks = 0; ks < 8; ++ks)
        d = __builtin_amdgcn_mfma_f32_16x16x32_f16(af[ks].v, Bs[ks].v, d, 0, 0, 0);
      // lane holds Pj[j=j0w+lo16][c_local = ct*16+kg*4+reg] -> b64 slab store
      U4 s;
#pragma unroll
      for (int r = 0; r < 4; ++r) s.f[r] = (_Float16)d[r];
      *(uint2*)((char*)&SlabS[w][0][0] + lo16 * 80 + ct * 32 + kg * 8) = s.u2;
    }

    // ---- Pi strip (waves 0,1: c-tiles 0,1), + b1 ----
    if (w < 2) {
      const int cl = w * 16 + lo16;  // c_local as B-col n
      U8 bf[8];
#pragma unroll
      for (int ks = 0; ks < 8; ++ks)
        bf[ks].f4 = *(const float4*)((const char*)WlS + cl * 512 +
                                     swz(cl, ks * 64 + kg * 16));
      int ar = i0 + lo16;
      if (ar > NSLOT - 1) ar = NSLOT - 1;  // rows >= i0+8 discarded (m<8 only)
      const float* srow = sb + (size_t)ar * DDIM;
      float4v pa = {0.0f, 0.0f, 0.0f, 0.0f};
#pragma unroll
      for (int ks = 0; ks < 8; ++ks) {
        const float4 x0 = *(const float4*)(srow + ks * 32 + kg * 8);
        const float4 x1 = *(const float4*)(srow + ks * 32 + kg * 8 + 4);
        U8 a;
        a.f[0] = (_Float16)x0.x; a.f[1] = (_Float16)x0.y;
        a.f[2] = (_Float16)x0.z; a.f[3] = (_Float16)x0.w;
        a.f[4] = (_Float16)x1.x; a.f[5] = (_Float16)x1.y;
        a.f[6] = (_Float16)x1.z; a.f[7] = (_Float16)x1.w;
        pa = __builtin_amdgcn_mfma_f32_16x16x32_f16(a.v, bf[ks].v, pa, 0, 0, 0);
      }
#pragma unroll
      for (int reg = 0; reg < 4; ++reg) {
        const int m = kg * 4 + reg;
        if (m < 8) PiS[m * 32 + cl] = (_Float16)(pa[reg] + b1[kq * 32 + cl]);
      }
    }

    __syncthreads();  // PiS visible; also fences W reads before next stage

    // ---- pair accumulate: one MFMA per i into persistent acc ----
    U8 pj;
    pj.f4 = *(const float4*)((const char*)&SlabS[w][0][0] + lo16 * 80 + kg * 16);
#pragma unroll
    for (int i = 0; i < 8; ++i) {
      U8 pif;
      pif.f4 = *(const float4*)((const char*)PiS + i * 64 + kg * 16);  // bcast
      U8 h;
      h.v = __builtin_elementwise_max(pj.v + pif.v, (half8)(_Float16)0.0f);
      acc[i] =
          __builtin_amdgcn_mfma_f32_16x16x32_f16(h.v, w2s.v, acc[i], 0, 0, 0);
    }
  }

  // ---- epilogue: sigmoid + stores (R14-validated indexing) ----
  if (lo16 < NREL) {
#pragma unroll
    for (int i = 0; i < 8; ++i) {
      float* obase =
          out + (((size_t)b * NSLOT + (i0 + i)) * NSLOT + j0w) * NREL + lo16;
#pragma unroll
      for (int reg = 0; reg < 4; ++reg) {
        const int jrow = kg * 4 + reg;
        const float x = acc[i][reg] + b2v;
        obase[jrow * NREL] = __builtin_amdgcn_rcpf(1.0f + __expf(-x));
      }
    }
  }
}

extern "C" void kernel_launch(void* const* d_in, const int* in_sizes, int n_in,
                              void* d_out, int out_size, void* d_ws,
                              size_t ws_size, hipStream_t stream) {
  const float* slots = (const float*)d_in[0];  // [8,256,256]
  const float* W1    = (const float*)d_in[1];  // [512,128]
  const float* b1    = (const float*)d_in[2];  // [128]
  const float* W2    = (const float*)d_in[3];  // [128,8]
  const float* b2    = (const float*)d_in[4];  // [8]
  float* out = (float*)d_out;                  // [8,256,256,8]
  (void)d_ws; (void)ws_size;                   // P never materialized

  fused_kernel<<<dim3(1024), 256, 0, stream>>>(slots, W1, b1, W2, b2, out);
}

// Round 5
// 82.508 us; speedup vs baseline: 1.5250x; 1.5250x over previous
//
#include <hip/hip_runtime.h>
#include <hip/hip_fp16.h>
#include <math.h>

#define BATCH 8
#define NSLOT 256
#define DDIM  256
#define HID   128
#define NREL  8
#define IT    4   // pair i-tile (R18: halved from 8 to double block count/TLP)

typedef _Float16 half8 __attribute__((ext_vector_type(8)));
typedef float float4v __attribute__((ext_vector_type(4)));

union U8 {
  uint32_t u[4];
  _Float16 f[8];
  half8 v;
  float4 f4;
};

// ---------------------------------------------------------------------------
// R18: back to the R14 two-kernel structure (best measured: 79.65us) with two
// TLP/VMEM fixes for the dominant pair kernel. Session evidence: fill poison
// (41.5us) + ~3us/dispatch are fixed; exec is latency-bound (R16: 42us exec at
// 19% occupancy, nothing near a roof; R17 regression: more barriers + W
// re-staging = worse). Changes vs R14:
//  1. pair i-tile 8 -> 4: 2048 blocks, 8 blocks/CU, 32 waves/CU (was 16).
//  2. pair W2 frags: 4x float4 from precomputed f16 W2T (R0-validated table,
//     built by proj block(0,0)) instead of 32 scalar dword loads.
// d_ws: P f16[2048][256] at 0 (1MB); W2T f16[16][128] at 1MB.
//
// MFMA maps (HW-validated R5-R12): A[m=lane&15][k=(lane>>4)*8+u],
//  B[k=(lane>>4)*8+u][n=lane&15], D[m=(lane>>4)*4+reg][n=lane&15].
// ---------------------------------------------------------------------------

// proj: P[r][c] = dot(slots[r], concatW[:,c]) + (c<128 ? b1[c] : 0)
//   concatW[k][c] = (c<128) ? W1[k][c] : W1[256+k][c-128]
// One wave per 16x16 output tile, 4 c-tiles per 256-thread block.
// Block (0,0) additionally builds W2T[n][k] = (f16)W2[k][n] (zero for n>=8).
__global__ __launch_bounds__(256) void proj_kernel(
    const float* __restrict__ slots, const float* __restrict__ W1,
    const float* __restrict__ b1, const float* __restrict__ W2,
    _Float16* __restrict__ P, _Float16* __restrict__ W2T) {
  const int lane = threadIdx.x & 63;
  const int w    = threadIdx.x >> 6;
  const int lo16 = lane & 15;
  const int kg   = lane >> 4;
  const int row0 = blockIdx.y * 16;
  const int c    = (blockIdx.x * 4 + w) * 16 + lo16;

  // B-frag: bf[ks].f[u] = concatW[ks*32+kg*8+u][c]  (stride-128 dword loads)
  const float* Wcol =
      (c < HID) ? (W1 + c) : (W1 + (size_t)DDIM * HID + (c - HID));
  U8 bf[8];
#pragma unroll
  for (int ks = 0; ks < 8; ++ks) {
    const int kb = ks * 32 + kg * 8;
#pragma unroll
    for (int u = 0; u < 8; ++u)
      bf[ks].f[u] = (_Float16)Wcol[(size_t)(kb + u) * HID];
  }

  float4v acc = {0.0f, 0.0f, 0.0f, 0.0f};
  const float* srow = slots + (size_t)(row0 + lo16) * DDIM;
#pragma unroll
  for (int ks = 0; ks < 8; ++ks) {
    const float4 x0 = *(const float4*)(srow + ks * 32 + kg * 8);
    const float4 x1 = *(const float4*)(srow + ks * 32 + kg * 8 + 4);
    U8 a;
    a.f[0] = (_Float16)x0.x; a.f[1] = (_Float16)x0.y;
    a.f[2] = (_Float16)x0.z; a.f[3] = (_Float16)x0.w;
    a.f[4] = (_Float16)x1.x; a.f[5] = (_Float16)x1.y;
    a.f[6] = (_Float16)x1.z; a.f[7] = (_Float16)x1.w;
    acc = __builtin_amdgcn_mfma_f32_16x16x32_f16(a.v, bf[ks].v, acc, 0, 0, 0);
  }

  const float bias = (c < HID) ? b1[c] : 0.0f;
#pragma unroll
  for (int reg = 0; reg < 4; ++reg)
    P[(size_t)(row0 + kg * 4 + reg) * 256 + c] = (_Float16)(acc[reg] + bias);

  // W2T build (R0-validated wt_kernel code): 16x128 f16, rows n>=8 zeroed.
  if (blockIdx.x == 0 && blockIdx.y == 0) {
#pragma unroll
    for (int p = 0; p < 8; ++p) {
      const int idx = threadIdx.x + p * 256;
      const int n = idx >> 7, k = idx & 127;
      W2T[n * 128 + k] = (n < 8) ? (_Float16)W2[k * NREL + n] : (_Float16)0.0f;
    }
  }
}

// pair (R14-validated body, IT=4): 2048 blocks x 256 thr (8 blocks/CU,
// 32 waves/CU), one tiny Pi LDS stage + one barrier, W2T 16B B-frags.
// out[b,i,j,r] = sigmoid( sum_k relu(P[b,i,k]+P[b,j,128+k]) * W2[k,r] + b2[r] )
__global__ __launch_bounds__(256) void pair_kernel(
    const _Float16* __restrict__ P, const _Float16* __restrict__ W2T,
    const float* __restrict__ b2, float* __restrict__ out) {
  __shared__ uint32_t PiL[IT * 68];

  const int tid  = threadIdx.x;
  const int w    = tid >> 6;
  const int lane = tid & 63;
  const int n    = lane & 15;
  const int kg   = lane >> 4;

  const int b  = blockIdx.z;
  const int i0 = blockIdx.y * IT;
  const int j0 = blockIdx.x * 64 + w * 16;
  const _Float16* Pb = P + (size_t)b * NSLOT * 256;

  if (tid < IT * 16) {  // stage Pi: IT rows x 128 f16
    const int r  = tid >> 4;
    const int ch = tid & 15;
    const float4 t = *(const float4*)(Pb + (size_t)(i0 + r) * 256 + ch * 8);
    *(float4*)&PiL[r * 68 + ch * 4] = t;
  }

  U8 w2f[4];
#pragma unroll
  for (int kq = 0; kq < 4; ++kq)
    w2f[kq].f4 = *(const float4*)(W2T + n * 128 + kq * 32 + kg * 8);

  const float b2v = (n < NREL) ? b2[n & 7] : 0.0f;

  U8 pj[4];
#pragma unroll
  for (int kq = 0; kq < 4; ++kq)
    pj[kq].f4 =
        *(const float4*)(Pb + (size_t)(j0 + n) * 256 + HID + kq * 32 + kg * 8);

  __syncthreads();

#pragma unroll
  for (int i = 0; i < IT; ++i) {
    float4v acc = {0.0f, 0.0f, 0.0f, 0.0f};
#pragma unroll
    for (int kq = 0; kq < 4; ++kq) {
      U8 pi;
      pi.f4 = *(const float4*)&PiL[i * 68 + kq * 16 + kg * 4];  // broadcast
      U8 h;
      h.v = __builtin_elementwise_max(pj[kq].v + pi.v, (half8)(_Float16)0.0f);
      acc = __builtin_amdgcn_mfma_f32_16x16x32_f16(h.v, w2f[kq].v, acc, 0, 0, 0);
    }
    if (n < NREL) {
      float* obase =
          out + (((size_t)b * NSLOT + (i0 + i)) * NSLOT + j0) * NREL + n;
#pragma unroll
      for (int reg = 0; reg < 4; ++reg) {
        const int jrow = kg * 4 + reg;
        const float x = acc[reg] + b2v;
        obase[jrow * NREL] = __builtin_amdgcn_rcpf(1.0f + __expf(-x));
      }
    }
  }
}

extern "C" void kernel_launch(void* const* d_in, const int* in_sizes, int n_in,
                              void* d_out, int out_size, void* d_ws,
                              size_t ws_size, hipStream_t stream) {
  const float* slots = (const float*)d_in[0];  // [8,256,256]
  const float* W1    = (const float*)d_in[1];  // [512,128]
  const float* b1    = (const float*)d_in[2];  // [128]
  const float* W2    = (const float*)d_in[3];  // [128,8]
  const float* b2    = (const float*)d_in[4];  // [8]
  float* out    = (float*)d_out;               // [8,256,256,8]
  _Float16* P   = (_Float16*)d_ws;                        // 1 MB
  _Float16* W2T = (_Float16*)((char*)d_ws + (1 << 20));   // 4 KB

  proj_kernel<<<dim3(4, 128), 256, 0, stream>>>(slots, W1, b1, W2, P, W2T);
  pair_kernel<<<dim3(NSLOT / 64, NSLOT / IT, BATCH), 256, 0, stream>>>(
      P, W2T, b2, out);
}